// Round 1
// baseline (408.434 us; speedup 1.0000x reference)
//
#include <hip/hip_runtime.h>
#include <hip/hip_bf16.h>

#define D 128

// ---------------------------------------------------------------------------
// Scatter-add: agg[src[e]][:] += edge_attr[e][:]
// 2 edges per 256-thread block; 128 threads per edge, 1 float each.
// Coalesced 512B reads; hardware f32 atomics (global_atomic_add_f32).
// ---------------------------------------------------------------------------
__global__ void scatter_kernel(const float* __restrict__ edge_attr,
                               const int* __restrict__ src,
                               float* __restrict__ agg, int nedges) {
    int e = blockIdx.x * 2 + (threadIdx.x >> 7);
    int lane = threadIdx.x & 127;
    if (e < nedges) {
        int s = src[e];
        unsafeAtomicAdd(&agg[(size_t)s * D + lane],
                        edge_attr[(size_t)e * D + lane]);
    }
}

// ---------------------------------------------------------------------------
// f32 GEMM: C[M,128] = act(A[M,K] @ W[K,128] + bias), optional SiLU,
// optional per-column sum/sumsq accumulation (for BatchNorm batch stats).
// K=256 reads columns 0..127 from A0 and 128..255 from A1 (implicit concat).
// Block tile: 64 rows x 128 cols, 256 threads, per-thread 8x4 micro-tile.
// A staged transposed in LDS (pad to 68 for alignment+banks), W staged row-major.
// ---------------------------------------------------------------------------
template <int K, bool SILU, bool STATS>
__global__ __launch_bounds__(256) void mlp_gemm(
    const float* __restrict__ A0, const float* __restrict__ A1,
    const float* __restrict__ W, const float* __restrict__ bias,
    float* __restrict__ C, float* __restrict__ gsum, float* __restrict__ gsq,
    int M) {
    __shared__ float As[32][68];   // [k][row], padded
    __shared__ float Ws[32][128];  // [k][col]

    const int tid = threadIdx.x;
    const int tx = tid & 31;   // col group (4 cols each)
    const int ty = tid >> 5;   // row group (8 rows each)
    const int row0 = blockIdx.x * 64;
    const int c0 = tx * 4;

    float bj[4];
    *(float4*)bj = *(const float4*)(bias + c0);
    float acc[8][4];
#pragma unroll
    for (int i = 0; i < 8; ++i)
#pragma unroll
        for (int j = 0; j < 4; ++j) acc[i][j] = bj[j];

    const int r_st = tid >> 3;       // 0..31
    const int kq = (tid & 7) * 4;    // 0,4,...,28

    for (int kc = 0; kc < K; kc += 32) {
        const float* Asrc;
        int kb;
        if (K == 256 && kc >= 128) { Asrc = A1; kb = kc - 128; }
        else                       { Asrc = A0; kb = kc; }
        // stage A-tile transposed: 64 rows x 32 k
#pragma unroll
        for (int p = 0; p < 2; ++p) {
            int r = p * 32 + r_st;
            int grow = row0 + r;
            float4 v = make_float4(0.f, 0.f, 0.f, 0.f);
            if (grow < M) v = *(const float4*)(Asrc + (size_t)grow * D + kb + kq);
            As[kq + 0][r] = v.x;
            As[kq + 1][r] = v.y;
            As[kq + 2][r] = v.z;
            As[kq + 3][r] = v.w;
        }
        // stage W-tile: 32 x 128 straight copy
        {
            const float4* Wg = (const float4*)(W + (size_t)kc * D);
            float4* Wl = (float4*)&Ws[0][0];
#pragma unroll
            for (int p = 0; p < 4; ++p) Wl[p * 256 + tid] = Wg[p * 256 + tid];
        }
        __syncthreads();
#pragma unroll 8
        for (int k = 0; k < 32; ++k) {
            float w[4];
            *(float4*)w = *(const float4*)&Ws[k][c0];
            float a[8];
            *(float4*)&a[0] = *(const float4*)&As[k][ty * 8];
            *(float4*)&a[4] = *(const float4*)&As[k][ty * 8 + 4];
#pragma unroll
            for (int i = 0; i < 8; ++i)
#pragma unroll
                for (int j = 0; j < 4; ++j)
                    acc[i][j] = fmaf(a[i], w[j], acc[i][j]);
        }
        __syncthreads();
    }

    // epilogue: activation, store, per-column stats
    float ssum[4] = {0.f, 0.f, 0.f, 0.f}, ssq[4] = {0.f, 0.f, 0.f, 0.f};
#pragma unroll
    for (int i = 0; i < 8; ++i) {
        int grow = row0 + ty * 8 + i;
        if (grow < M) {
            float o[4];
#pragma unroll
            for (int j = 0; j < 4; ++j) {
                float v = acc[i][j];
                if (SILU) v = v / (1.0f + __expf(-v));
                o[j] = v;
                if (STATS) { ssum[j] += v; ssq[j] += v * v; }
            }
            *(float4*)(C + (size_t)grow * D + c0) = *(float4*)o;
        }
    }

    if (STATS) {
        __syncthreads();
        float* red = &Ws[0][0];  // 4096 floats of LDS, reuse
#pragma unroll
        for (int j = 0; j < 4; ++j) {
            red[(c0 + j) * 8 + ty] = ssum[j];
            red[1024 + (c0 + j) * 8 + ty] = ssq[j];
        }
        __syncthreads();
        // 256 threads: t<128 -> column-sum t ; t>=128 -> column-sumsq t-128
        float v = 0.f;
        int base = tid * 8;
#pragma unroll
        for (int u = 0; u < 8; ++u) v += red[base + u];
        if (tid < 128) unsafeAtomicAdd(&gsum[tid], v);
        else           unsafeAtomicAdd(&gsq[tid - 128], v);
    }
}

// ---------------------------------------------------------------------------
// Fold BN (training-mode batch stats) into the next layer's weights:
//   scale[k] = gamma[k] * rsqrt(var[k]+eps); shift[k] = beta[k]-mean[k]*scale[k]
//   Wf[k][j] = scale[k]*W[k][j];  bf[j] = b[j] + sum_k shift[k]*W[k][j]
// grid = 128 blocks (one per output col j), 128 threads (one per k).
// ---------------------------------------------------------------------------
__global__ void fold_kernel(const float* __restrict__ sum,
                            const float* __restrict__ sq,
                            const float* __restrict__ gamma,
                            const float* __restrict__ beta,
                            const float* __restrict__ W,
                            const float* __restrict__ b,
                            float* __restrict__ Wf, float* __restrict__ bf,
                            float invM) {
    int j = blockIdx.x;
    int k = threadIdx.x;
    float mean = sum[k] * invM;
    float var = sq[k] * invM - mean * mean;
    float scale = gamma[k] * rsqrtf(var + 1e-5f);
    float shift = beta[k] - mean * scale;
    float w = W[k * D + j];
    Wf[k * D + j] = scale * w;
    float v = shift * w;
#pragma unroll
    for (int off = 32; off; off >>= 1) v += __shfl_down(v, off);
    __shared__ float ws2[2];
    if ((k & 63) == 0) ws2[k >> 6] = v;
    __syncthreads();
    if (k == 0) bf[j] = b[j] + ws2[0] + ws2[1];
}

extern "C" void kernel_launch(void* const* d_in, const int* in_sizes, int n_in,
                              void* d_out, int out_size, void* d_ws,
                              size_t ws_size, hipStream_t stream) {
    const float* x     = (const float*)d_in[0];
    const int*   eidx  = (const int*)d_in[1];
    const float* eattr = (const float*)d_in[2];
    const float* W1  = (const float*)d_in[3];
    const float* b1  = (const float*)d_in[4];
    const float* g1  = (const float*)d_in[5];
    const float* be1 = (const float*)d_in[6];
    const float* W2  = (const float*)d_in[7];
    const float* b2  = (const float*)d_in[8];
    const float* g2  = (const float*)d_in[9];
    const float* be2 = (const float*)d_in[10];
    const float* W3  = (const float*)d_in[11];
    const float* b3  = (const float*)d_in[12];

    const int M = in_sizes[0] / D;   // 50000 nodes
    const int E = in_sizes[1] / 2;   // 600000 edges
    const int* srcIdx = eidx;        // edge_index[0] = first E ints

    float* ws   = (float*)d_ws;
    float* agg  = ws;                        // M*D
    float* h1   = agg + (size_t)M * D;       // M*D
    float* sum1 = h1 + (size_t)M * D;        // D
    float* sq1  = sum1 + D;                  // D
    float* sum2 = sq1 + D;                   // D
    float* sq2  = sum2 + D;                  // D
    float* W2f  = sq2 + D;                   // D*D
    float* b2f  = W2f + (size_t)D * D;       // D
    float* W3f  = b2f + D;                   // D*D
    float* b3f  = W3f + (size_t)D * D;       // D

    float* out = (float*)d_out;
    float* h2  = out;  // alias: safe (disjoint row-blocks, reads precede writes)

    hipMemsetAsync(agg, 0, (size_t)M * D * sizeof(float), stream);
    hipMemsetAsync(sum1, 0, 4 * D * sizeof(float), stream);

    scatter_kernel<<<(E + 1) / 2, 256, 0, stream>>>(eattr, srcIdx, agg, E);

    int nblk = (M + 63) / 64;
    mlp_gemm<256, true, true><<<nblk, 256, 0, stream>>>(
        x, agg, W1, b1, h1, sum1, sq1, M);
    fold_kernel<<<D, D, 0, stream>>>(sum1, sq1, g1, be1, W2, b2, W2f, b2f,
                                     1.0f / (float)M);
    mlp_gemm<128, true, true><<<nblk, 256, 0, stream>>>(
        h1, nullptr, W2f, b2f, h2, sum2, sq2, M);
    fold_kernel<<<D, D, 0, stream>>>(sum2, sq2, g2, be2, W3, b3, W3f, b3f,
                                     1.0f / (float)M);
    mlp_gemm<128, false, false><<<nblk, 256, 0, stream>>>(
        h2, nullptr, W3f, b3f, out, nullptr, nullptr, M);
}

// Round 2
// 405.913 us; speedup vs baseline: 1.0062x; 1.0062x over previous
//
#include <hip/hip_runtime.h>
#include <hip/hip_bf16.h>

#define D 128

// ---------------------------------------------------------------------------
// CSR build, pass 1: histogram of edge source nodes.
// ---------------------------------------------------------------------------
__global__ void hist_kernel(const int* __restrict__ src,
                            int* __restrict__ counts, int nedges) {
    int e = blockIdx.x * 256 + threadIdx.x;
    if (e < nedges) atomicAdd(&counts[src[e]], 1);
}

// ---------------------------------------------------------------------------
// CSR build, pass 2: single-block exclusive scan of counts[n] -> off[n+1],
// and a second copy into cur[n] (atomic cursors for the fill pass).
// n = 50000: each of 1024 threads serially handles ~49 elements, then a
// Hillis-Steele block scan over the 1024 partial sums.
// ---------------------------------------------------------------------------
__global__ __launch_bounds__(1024) void scan_kernel(
    const int* __restrict__ counts, int* __restrict__ off,
    int* __restrict__ cur, int n) {
    __shared__ int sdata[1024];
    const int tid = threadIdx.x;
    const int per = (n + 1023) / 1024;
    const int lo = min(tid * per, n);
    const int hi = min(lo + per, n);
    int sum = 0;
    for (int i = lo; i < hi; ++i) sum += counts[i];
    sdata[tid] = sum;
    __syncthreads();
#pragma unroll
    for (int d = 1; d < 1024; d <<= 1) {
        int v = (tid >= d) ? sdata[tid - d] : 0;
        __syncthreads();
        sdata[tid] += v;
        __syncthreads();
    }
    int pre = (tid == 0) ? 0 : sdata[tid - 1];
    for (int i = lo; i < hi; ++i) {
        off[i] = pre;
        cur[i] = pre;
        pre += counts[i];
    }
    if (tid == 0) off[n] = sdata[1023];
}

// ---------------------------------------------------------------------------
// CSR build, pass 3: bin edge ids by source node.
// ---------------------------------------------------------------------------
__global__ void fill_kernel(const int* __restrict__ src, int* __restrict__ cur,
                            int* __restrict__ eid, int nedges) {
    int e = blockIdx.x * 256 + threadIdx.x;
    if (e < nedges) {
        int slot = atomicAdd(&cur[src[e]], 1);
        eid[slot] = e;
    }
}

// ---------------------------------------------------------------------------
// Gather: agg[n][:] = sum over this node's edges of edge_attr[eid][:].
// One wave (64 lanes) per node; each lane owns a float2 column pair.
// Each edge row is a single coalesced 512B read; no atomics anywhere.
// ---------------------------------------------------------------------------
__global__ __launch_bounds__(256) void gather_kernel(
    const float* __restrict__ edge_attr, const int* __restrict__ eid,
    const int* __restrict__ off, float* __restrict__ agg, int nnodes) {
    int node = blockIdx.x * 4 + (threadIdx.x >> 6);
    int lane = threadIdx.x & 63;
    if (node >= nnodes) return;
    int s = off[node];
    int e = off[node + 1];
    float2 acc = make_float2(0.f, 0.f);
    int i = s;
    for (; i + 2 <= e; i += 2) {  // unroll-2: two independent row loads in flight
        int e0 = eid[i], e1 = eid[i + 1];
        float2 v0 = *((const float2*)(edge_attr + (size_t)e0 * D) + lane);
        float2 v1 = *((const float2*)(edge_attr + (size_t)e1 * D) + lane);
        acc.x += v0.x + v1.x;
        acc.y += v0.y + v1.y;
    }
    if (i < e) {
        float2 v = *((const float2*)(edge_attr + (size_t)eid[i] * D) + lane);
        acc.x += v.x;
        acc.y += v.y;
    }
    *((float2*)(agg + (size_t)node * D) + lane) = acc;
}

// ---------------------------------------------------------------------------
// f32 GEMM: C[M,128] = act(A[M,K] @ W[K,128] + bias), optional SiLU,
// optional per-column sum/sumsq accumulation (for BatchNorm batch stats).
// K=256 reads columns 0..127 from A0 and 128..255 from A1 (implicit concat).
// Block tile: 64 rows x 128 cols, 256 threads, per-thread 8x4 micro-tile.
// ---------------------------------------------------------------------------
template <int K, bool SILU, bool STATS>
__global__ __launch_bounds__(256) void mlp_gemm(
    const float* __restrict__ A0, const float* __restrict__ A1,
    const float* __restrict__ W, const float* __restrict__ bias,
    float* __restrict__ C, float* __restrict__ gsum, float* __restrict__ gsq,
    int M) {
    __shared__ float As[32][68];   // [k][row], padded
    __shared__ float Ws[32][128];  // [k][col]

    const int tid = threadIdx.x;
    const int tx = tid & 31;   // col group (4 cols each)
    const int ty = tid >> 5;   // row group (8 rows each)
    const int row0 = blockIdx.x * 64;
    const int c0 = tx * 4;

    float bj[4];
    *(float4*)bj = *(const float4*)(bias + c0);
    float acc[8][4];
#pragma unroll
    for (int i = 0; i < 8; ++i)
#pragma unroll
        for (int j = 0; j < 4; ++j) acc[i][j] = bj[j];

    const int r_st = tid >> 3;       // 0..31
    const int kq = (tid & 7) * 4;    // 0,4,...,28

    for (int kc = 0; kc < K; kc += 32) {
        const float* Asrc;
        int kb;
        if (K == 256 && kc >= 128) { Asrc = A1; kb = kc - 128; }
        else                       { Asrc = A0; kb = kc; }
#pragma unroll
        for (int p = 0; p < 2; ++p) {
            int r = p * 32 + r_st;
            int grow = row0 + r;
            float4 v = make_float4(0.f, 0.f, 0.f, 0.f);
            if (grow < M) v = *(const float4*)(Asrc + (size_t)grow * D + kb + kq);
            As[kq + 0][r] = v.x;
            As[kq + 1][r] = v.y;
            As[kq + 2][r] = v.z;
            As[kq + 3][r] = v.w;
        }
        {
            const float4* Wg = (const float4*)(W + (size_t)kc * D);
            float4* Wl = (float4*)&Ws[0][0];
#pragma unroll
            for (int p = 0; p < 4; ++p) Wl[p * 256 + tid] = Wg[p * 256 + tid];
        }
        __syncthreads();
#pragma unroll 8
        for (int k = 0; k < 32; ++k) {
            float w[4];
            *(float4*)w = *(const float4*)&Ws[k][c0];
            float a[8];
            *(float4*)&a[0] = *(const float4*)&As[k][ty * 8];
            *(float4*)&a[4] = *(const float4*)&As[k][ty * 8 + 4];
#pragma unroll
            for (int i = 0; i < 8; ++i)
#pragma unroll
                for (int j = 0; j < 4; ++j)
                    acc[i][j] = fmaf(a[i], w[j], acc[i][j]);
        }
        __syncthreads();
    }

    float ssum[4] = {0.f, 0.f, 0.f, 0.f}, ssq[4] = {0.f, 0.f, 0.f, 0.f};
#pragma unroll
    for (int i = 0; i < 8; ++i) {
        int grow = row0 + ty * 8 + i;
        if (grow < M) {
            float o[4];
#pragma unroll
            for (int j = 0; j < 4; ++j) {
                float v = acc[i][j];
                if (SILU) v = v / (1.0f + __expf(-v));
                o[j] = v;
                if (STATS) { ssum[j] += v; ssq[j] += v * v; }
            }
            *(float4*)(C + (size_t)grow * D + c0) = *(float4*)o;
        }
    }

    if (STATS) {
        __syncthreads();
        float* red = &Ws[0][0];
#pragma unroll
        for (int j = 0; j < 4; ++j) {
            red[(c0 + j) * 8 + ty] = ssum[j];
            red[1024 + (c0 + j) * 8 + ty] = ssq[j];
        }
        __syncthreads();
        float v = 0.f;
        int base = tid * 8;
#pragma unroll
        for (int u = 0; u < 8; ++u) v += red[base + u];
        if (tid < 128) unsafeAtomicAdd(&gsum[tid], v);
        else           unsafeAtomicAdd(&gsq[tid - 128], v);
    }
}

// ---------------------------------------------------------------------------
// Fold BN (batch stats) into the next layer's weights.
// ---------------------------------------------------------------------------
__global__ void fold_kernel(const float* __restrict__ sum,
                            const float* __restrict__ sq,
                            const float* __restrict__ gamma,
                            const float* __restrict__ beta,
                            const float* __restrict__ W,
                            const float* __restrict__ b,
                            float* __restrict__ Wf, float* __restrict__ bf,
                            float invM) {
    int j = blockIdx.x;
    int k = threadIdx.x;
    float mean = sum[k] * invM;
    float var = sq[k] * invM - mean * mean;
    float scale = gamma[k] * rsqrtf(var + 1e-5f);
    float shift = beta[k] - mean * scale;
    float w = W[k * D + j];
    Wf[k * D + j] = scale * w;
    float v = shift * w;
#pragma unroll
    for (int off = 32; off; off >>= 1) v += __shfl_down(v, off);
    __shared__ float ws2[2];
    if ((k & 63) == 0) ws2[k >> 6] = v;
    __syncthreads();
    if (k == 0) bf[j] = b[j] + ws2[0] + ws2[1];
}

extern "C" void kernel_launch(void* const* d_in, const int* in_sizes, int n_in,
                              void* d_out, int out_size, void* d_ws,
                              size_t ws_size, hipStream_t stream) {
    const float* x     = (const float*)d_in[0];
    const int*   eidx  = (const int*)d_in[1];
    const float* eattr = (const float*)d_in[2];
    const float* W1  = (const float*)d_in[3];
    const float* b1  = (const float*)d_in[4];
    const float* g1  = (const float*)d_in[5];
    const float* be1 = (const float*)d_in[6];
    const float* W2  = (const float*)d_in[7];
    const float* b2  = (const float*)d_in[8];
    const float* g2  = (const float*)d_in[9];
    const float* be2 = (const float*)d_in[10];
    const float* W3  = (const float*)d_in[11];
    const float* b3  = (const float*)d_in[12];

    const int M = in_sizes[0] / D;   // 50000 nodes
    const int E = in_sizes[1] / 2;   // 600000 edges
    const int* srcIdx = eidx;        // edge_index[0] = first E ints

    float* ws   = (float*)d_ws;
    float* agg  = ws;                        // M*D floats
    float* h1   = agg + (size_t)M * D;       // M*D
    float* sum1 = h1 + (size_t)M * D;        // D
    float* sq1  = sum1 + D;
    float* sum2 = sq1 + D;
    float* sq2  = sum2 + D;
    float* W2f  = sq2 + D;                   // D*D
    float* b2f  = W2f + (size_t)D * D;       // D
    float* W3f  = b2f + D;                   // D*D
    float* b3f  = W3f + (size_t)D * D;       // D
    int* counts = (int*)(b3f + D);           // M
    int* off    = counts + M;                // M+1
    int* cur    = off + M + 1;               // M
    int* eid    = cur + M;                   // E

    float* out = (float*)d_out;
    float* h2  = out;  // alias: safe (disjoint row-blocks, reads precede writes)

    hipMemsetAsync(counts, 0, (size_t)M * sizeof(int), stream);
    hipMemsetAsync(sum1, 0, 4 * D * sizeof(float), stream);

    int eblk = (E + 255) / 256;
    hist_kernel<<<eblk, 256, 0, stream>>>(srcIdx, counts, E);
    scan_kernel<<<1, 1024, 0, stream>>>(counts, off, cur, M);
    fill_kernel<<<eblk, 256, 0, stream>>>(srcIdx, cur, eid, E);
    gather_kernel<<<(M + 3) / 4, 256, 0, stream>>>(eattr, eid, off, agg, M);

    int nblk = (M + 63) / 64;
    mlp_gemm<256, true, true><<<nblk, 256, 0, stream>>>(
        x, agg, W1, b1, h1, sum1, sq1, M);
    fold_kernel<<<D, D, 0, stream>>>(sum1, sq1, g1, be1, W2, b2, W2f, b2f,
                                     1.0f / (float)M);
    mlp_gemm<128, true, true><<<nblk, 256, 0, stream>>>(
        h1, nullptr, W2f, b2f, h2, sum2, sq2, M);
    fold_kernel<<<D, D, 0, stream>>>(sum2, sq2, g2, be2, W3, b3, W3f, b3f,
                                     1.0f / (float)M);
    mlp_gemm<128, false, false><<<nblk, 256, 0, stream>>>(
        h2, nullptr, W3f, b3f, out, nullptr, nullptr, M);
}

// Round 3
// 393.988 us; speedup vs baseline: 1.0367x; 1.0303x over previous
//
#include <hip/hip_runtime.h>
#include <hip/hip_bf16.h>

#define D 128

typedef __attribute__((ext_vector_type(8))) short bfrag;   // 8 bf16 (4 VGPRs)
typedef __attribute__((ext_vector_type(4))) float facc;    // 4 f32 acc

__device__ __forceinline__ facc mfma16(bfrag a, bfrag b, facc c) {
    return __builtin_amdgcn_mfma_f32_16x16x32_bf16(a, b, c, 0, 0, 0);
}
__device__ __forceinline__ unsigned short bf16_rn(float f) {
    unsigned int u = __float_as_uint(f);
    u += 0x7FFF + ((u >> 16) & 1);   // round-nearest-even
    return (unsigned short)(u >> 16);
}
__device__ __forceinline__ float bf16_f(unsigned short h) {
    return __uint_as_float(((unsigned int)h) << 16);
}

// ---------------------------------------------------------------------------
// CSR build, pass 1: histogram of edge source nodes.
// ---------------------------------------------------------------------------
__global__ void hist_kernel(const int* __restrict__ src,
                            int* __restrict__ counts, int nedges) {
    int e = blockIdx.x * 256 + threadIdx.x;
    if (e < nedges) atomicAdd(&counts[src[e]], 1);
}

// ---------------------------------------------------------------------------
// CSR build, pass 2: single-block exclusive scan -> off[n+1] and cursors.
// ---------------------------------------------------------------------------
__global__ __launch_bounds__(1024) void scan_kernel(
    const int* __restrict__ counts, int* __restrict__ off,
    int* __restrict__ cur, int n) {
    __shared__ int sdata[1024];
    const int tid = threadIdx.x;
    const int per = (n + 1023) / 1024;
    const int lo = min(tid * per, n);
    const int hi = min(lo + per, n);
    int sum = 0;
#pragma unroll 4
    for (int i = lo; i < hi; ++i) sum += counts[i];
    sdata[tid] = sum;
    __syncthreads();
#pragma unroll
    for (int d = 1; d < 1024; d <<= 1) {
        int v = (tid >= d) ? sdata[tid - d] : 0;
        __syncthreads();
        sdata[tid] += v;
        __syncthreads();
    }
    int pre = (tid == 0) ? 0 : sdata[tid - 1];
#pragma unroll 4
    for (int i = lo; i < hi; ++i) {
        off[i] = pre;
        cur[i] = pre;
        pre += counts[i];
    }
    if (tid == 0) off[n] = sdata[1023];
}

// ---------------------------------------------------------------------------
// CSR build, pass 3: bin edge ids by source node.
// ---------------------------------------------------------------------------
__global__ void fill_kernel(const int* __restrict__ src, int* __restrict__ cur,
                            int* __restrict__ eid, int nedges) {
    int e = blockIdx.x * 256 + threadIdx.x;
    if (e < nedges) {
        int slot = atomicAdd(&cur[src[e]], 1);
        eid[slot] = e;
    }
}

// ---------------------------------------------------------------------------
// Gather: agg[n][:] = sum over node n's edges of edge_attr rows. One wave per
// node, float2 per lane (512B coalesced row reads), unroll-4 for MLP.
// ---------------------------------------------------------------------------
__global__ __launch_bounds__(256) void gather_kernel(
    const float* __restrict__ edge_attr, const int* __restrict__ eid,
    const int* __restrict__ off, float* __restrict__ agg, int nnodes) {
    int node = blockIdx.x * 4 + (threadIdx.x >> 6);
    int lane = threadIdx.x & 63;
    if (node >= nnodes) return;
    int s = off[node];
    int e = off[node + 1];
    float2 acc = make_float2(0.f, 0.f);
    int i = s;
    for (; i + 4 <= e; i += 4) {
        int e0 = eid[i], e1 = eid[i + 1], e2 = eid[i + 2], e3 = eid[i + 3];
        float2 v0 = *((const float2*)(edge_attr + (size_t)e0 * D) + lane);
        float2 v1 = *((const float2*)(edge_attr + (size_t)e1 * D) + lane);
        float2 v2 = *((const float2*)(edge_attr + (size_t)e2 * D) + lane);
        float2 v3 = *((const float2*)(edge_attr + (size_t)e3 * D) + lane);
        acc.x += (v0.x + v1.x) + (v2.x + v3.x);
        acc.y += (v0.y + v1.y) + (v2.y + v3.y);
    }
    for (; i < e; ++i) {
        float2 v = *((const float2*)(edge_attr + (size_t)eid[i] * D) + lane);
        acc.x += v.x;
        acc.y += v.y;
    }
    *((float2*)(agg + (size_t)node * D) + lane) = acc;
}

// ---------------------------------------------------------------------------
// Split W1 (f32 [K][128]) into transposed bf16 hi/lo planes [128][K].
// grid = 128 (col j), block = K threads (k).
// ---------------------------------------------------------------------------
__global__ void prep_w_kernel(const float* __restrict__ W,
                              unsigned short* __restrict__ Whi,
                              unsigned short* __restrict__ Wlo, int K) {
    int j = blockIdx.x;
    int k = threadIdx.x;
    float w = W[(size_t)k * D + j];
    unsigned short hi = bf16_rn(w);
    Whi[(size_t)j * K + k] = hi;
    Wlo[(size_t)j * K + k] = bf16_rn(w - bf16_f(hi));
}

// ---------------------------------------------------------------------------
// Fold BN (batch stats) into next layer's W; emit transposed split-bf16 W
// and f32 bias. grid = 128 (col j), block = 128 (k).
// ---------------------------------------------------------------------------
__global__ void fold_kernel(const float* __restrict__ sum,
                            const float* __restrict__ sq,
                            const float* __restrict__ gamma,
                            const float* __restrict__ beta,
                            const float* __restrict__ W,
                            const float* __restrict__ b,
                            unsigned short* __restrict__ Whi,
                            unsigned short* __restrict__ Wlo,
                            float* __restrict__ bf, float invM) {
    int j = blockIdx.x;
    int k = threadIdx.x;
    float mean = sum[k] * invM;
    float var = sq[k] * invM - mean * mean;
    float scale = gamma[k] * rsqrtf(var + 1e-5f);
    float shift = beta[k] - mean * scale;
    float w = W[k * D + j];
    float wf = scale * w;
    unsigned short hi = bf16_rn(wf);
    Whi[j * D + k] = hi;
    Wlo[j * D + k] = bf16_rn(wf - bf16_f(hi));
    float v = shift * w;
#pragma unroll
    for (int o = 32; o; o >>= 1) v += __shfl_down(v, o);
    __shared__ float ws2[2];
    if ((k & 63) == 0) ws2[k >> 6] = v;
    __syncthreads();
    if (k == 0) bf[j] = b[j] + ws2[0] + ws2[1];
}

// ---------------------------------------------------------------------------
// Split-bf16 MFMA GEMM: C[M,128] = act(A[M,K] @ Wt^T + bias).
// Wt is pre-split/transposed bf16 [128][K] (hi/lo). A is f32, split on the
// fly; 3 MFMAs (Ahi*Whi + Ahi*Wlo + Alo*Whi) per 16x16x32 tile -> ~f32 acc.
// Block = 256 thr = 4 waves, BM = 64 (wave w owns rows w*16..w*16+15 for all
// 8 col-tiles). LDS-free: A-frags direct from global (each 128B row-line
// fully consumed by the 4 lane-groups), B-frags 16B register loads (L2-hot).
// K==256 reads k<128 from A0, k>=128 from A1 (implicit concat).
// C/D layout (m89): col = lane&15, row = (lane>>4)*4 + reg.
// ---------------------------------------------------------------------------
template <int K, bool SILU, bool STATS>
__global__ __launch_bounds__(256) void mlp_gemm_mfma(
    const float* __restrict__ A0, const float* __restrict__ A1,
    const unsigned short* __restrict__ Whi,
    const unsigned short* __restrict__ Wlo,
    const float* __restrict__ bias, float* __restrict__ C,
    float* __restrict__ gsum, float* __restrict__ gsq, int M) {
    const int tid = threadIdx.x;
    const int w = tid >> 6;
    const int l = tid & 63;
    const int lr = l & 15;   // A row-in-tile / B col-in-tile
    const int lk = l >> 4;   // k-block 0..3
    const int arow = blockIdx.x * 64 + w * 16 + lr;

    facc acc[8];
#pragma unroll
    for (int ct = 0; ct < 8; ++ct)
#pragma unroll
        for (int r = 0; r < 4; ++r) acc[ct][r] = 0.f;

    const int NS = K / 32;
    float4 a0, a1, n0, n1;

    auto loadA = [&](int s, float4& x0, float4& x1) {
        int kb = s * 32 + lk * 8;
        const float* src = A0;
        if (K == 256 && kb >= 128) { src = A1; kb -= 128; }
        if (arow < M) {
            const float* p = src + (size_t)arow * D + kb;
            x0 = *(const float4*)p;
            x1 = *(const float4*)(p + 4);
        } else {
            x0 = make_float4(0.f, 0.f, 0.f, 0.f);
            x1 = x0;
        }
    };

    loadA(0, a0, a1);
    for (int s = 0; s < NS; ++s) {
        if (s + 1 < NS) loadA(s + 1, n0, n1);
        float av[8] = {a0.x, a0.y, a0.z, a0.w, a1.x, a1.y, a1.z, a1.w};
        bfrag ahi, alo;
#pragma unroll
        for (int i = 0; i < 8; ++i) {
            unsigned short h = bf16_rn(av[i]);
            ahi[i] = (short)h;
            alo[i] = (short)bf16_rn(av[i] - bf16_f(h));
        }
        const int kb = s * 32 + lk * 8;
        bfrag bhi[8], blo[8];
#pragma unroll
        for (int ct = 0; ct < 8; ++ct) {
            size_t boff = (size_t)(ct * 16 + lr) * K + kb;
            bhi[ct] = *(const bfrag*)(Whi + boff);
            blo[ct] = *(const bfrag*)(Wlo + boff);
        }
#pragma unroll
        for (int ct = 0; ct < 8; ++ct) acc[ct] = mfma16(ahi, bhi[ct], acc[ct]);
#pragma unroll
        for (int ct = 0; ct < 8; ++ct) acc[ct] = mfma16(ahi, blo[ct], acc[ct]);
#pragma unroll
        for (int ct = 0; ct < 8; ++ct) acc[ct] = mfma16(alo, bhi[ct], acc[ct]);
        a0 = n0;
        a1 = n1;
    }

    // Epilogue. C rows for this lane: crow0 + r; col = ct*16 + lr.
    const int crow0 = blockIdx.x * 64 + w * 16 + lk * 4;
    __shared__ float sred[2][4][128];
#pragma unroll
    for (int ct = 0; ct < 8; ++ct) {
        const int col = ct * 16 + lr;
        const float bj = bias[col];
        float s = 0.f, q = 0.f;
#pragma unroll
        for (int r = 0; r < 4; ++r) {
            int crow = crow0 + r;
            if (crow < M) {
                float v = acc[ct][r] + bj;
                if (SILU) v = v / (1.0f + __expf(-v));
                C[(size_t)crow * D + col] = v;
                if (STATS) { s += v; q += v * v; }
            }
        }
        if (STATS) {
            s += __shfl_xor(s, 16);
            s += __shfl_xor(s, 32);
            q += __shfl_xor(q, 16);
            q += __shfl_xor(q, 32);
            if (lk == 0) {
                sred[0][w][col] = s;
                sred[1][w][col] = q;
            }
        }
    }
    if (STATS) {
        __syncthreads();
        if (tid < 128) {
            float v = sred[0][0][tid] + sred[0][1][tid] + sred[0][2][tid] +
                      sred[0][3][tid];
            unsafeAtomicAdd(&gsum[tid], v);
        } else {
            int c = tid - 128;
            float v = sred[1][0][c] + sred[1][1][c] + sred[1][2][c] +
                      sred[1][3][c];
            unsafeAtomicAdd(&gsq[c], v);
        }
    }
}

extern "C" void kernel_launch(void* const* d_in, const int* in_sizes, int n_in,
                              void* d_out, int out_size, void* d_ws,
                              size_t ws_size, hipStream_t stream) {
    const float* x     = (const float*)d_in[0];
    const int*   eidx  = (const int*)d_in[1];
    const float* eattr = (const float*)d_in[2];
    const float* W1  = (const float*)d_in[3];
    const float* b1  = (const float*)d_in[4];
    const float* g1  = (const float*)d_in[5];
    const float* be1 = (const float*)d_in[6];
    const float* W2  = (const float*)d_in[7];
    const float* b2  = (const float*)d_in[8];
    const float* g2  = (const float*)d_in[9];
    const float* be2 = (const float*)d_in[10];
    const float* W3  = (const float*)d_in[11];
    const float* b3  = (const float*)d_in[12];

    const int M = in_sizes[0] / D;   // 50000
    const int E = in_sizes[1] / 2;   // 600000
    const int* srcIdx = eidx;

    float* ws   = (float*)d_ws;
    float* agg  = ws;                        // M*D
    float* h1   = agg + (size_t)M * D;       // M*D
    float* sum1 = h1 + (size_t)M * D;        // D
    float* sq1  = sum1 + D;
    float* sum2 = sq1 + D;
    float* sq2  = sum2 + D;
    float* b2f  = sq2 + D;                   // D
    float* b3f  = b2f + D;                   // D
    int* counts = (int*)(b3f + D);           // M
    int* off    = counts + M;                // M+1 (+pad)
    int* cur    = off + M + 4;               // M
    int* eid    = cur + M;                   // E
    unsigned short* W1h = (unsigned short*)(eid + E);  // 128*256
    unsigned short* W1l = W1h + 256 * D;
    unsigned short* W2h = W1l + 256 * D;               // 128*128
    unsigned short* W2l = W2h + D * D;
    unsigned short* W3h = W2l + D * D;
    unsigned short* W3l = W3h + D * D;

    float* out = (float*)d_out;
    float* h2  = out;  // alias: disjoint row-blocks, block reads precede writes

    hipMemsetAsync(counts, 0, (size_t)M * sizeof(int), stream);
    hipMemsetAsync(sum1, 0, 4 * D * sizeof(float), stream);

    int eblk = (E + 255) / 256;
    hist_kernel<<<eblk, 256, 0, stream>>>(srcIdx, counts, E);
    scan_kernel<<<1, 1024, 0, stream>>>(counts, off, cur, M);
    fill_kernel<<<eblk, 256, 0, stream>>>(srcIdx, cur, eid, E);
    gather_kernel<<<(M + 3) / 4, 256, 0, stream>>>(eattr, eid, off, agg, M);

    prep_w_kernel<<<D, 256, 0, stream>>>(W1, W1h, W1l, 256);

    int nblk = (M + 63) / 64;
    mlp_gemm_mfma<256, true, true><<<nblk, 256, 0, stream>>>(
        x, agg, W1h, W1l, b1, h1, sum1, sq1, M);
    fold_kernel<<<D, D, 0, stream>>>(sum1, sq1, g1, be1, W2, b2, W2h, W2l,
                                     b2f, 1.0f / (float)M);
    mlp_gemm_mfma<128, true, true><<<nblk, 256, 0, stream>>>(
        h1, nullptr, W2h, W2l, b2f, h2, sum2, sq2, M);
    fold_kernel<<<D, D, 0, stream>>>(sum2, sq2, g2, be2, W3, b3, W3h, W3l,
                                     b3f, 1.0f / (float)M);
    mlp_gemm_mfma<128, false, false><<<nblk, 256, 0, stream>>>(
        h2, nullptr, W3h, W3l, b3f, out, nullptr, nullptr, M);
}

// Round 4
// 289.843 us; speedup vs baseline: 1.4092x; 1.3593x over previous
//
#include <hip/hip_runtime.h>
#include <hip/hip_bf16.h>

#define D 128

typedef __attribute__((ext_vector_type(8))) short bfrag;   // 8 bf16 (4 VGPRs)
typedef __attribute__((ext_vector_type(4))) float facc;    // 4 f32 acc
typedef __attribute__((ext_vector_type(4))) unsigned int u32x4;

__device__ __forceinline__ facc mfma16(bfrag a, bfrag b, facc c) {
    return __builtin_amdgcn_mfma_f32_16x16x32_bf16(a, b, c, 0, 0, 0);
}
__device__ __forceinline__ unsigned int bf16_rn(float f) {
    unsigned int u = __float_as_uint(f);
    u += 0x7FFF + ((u >> 16) & 1);   // round-nearest-even
    return u >> 16;
}
__device__ __forceinline__ float bf16_f(unsigned int h) {
    return __uint_as_float(h << 16);
}
// pack f32 -> (bf16_hi << 16) | bf16_lo  (hi + lo reconstructs ~f32)
__device__ __forceinline__ unsigned int packf(float v) {
    unsigned int hi = bf16_rn(v);
    unsigned int lo = bf16_rn(v - bf16_f(hi));
    return (hi << 16) | lo;
}

// ---------------------------------------------------------------------------
// CSR build, pass 1: histogram of edge source nodes.
// ---------------------------------------------------------------------------
__global__ void hist_kernel(const int* __restrict__ src,
                            int* __restrict__ counts, int nedges) {
    int e = blockIdx.x * 256 + threadIdx.x;
    if (e < nedges) atomicAdd(&counts[src[e]], 1);
}

// ---------------------------------------------------------------------------
// CSR build, pass 2: single-block exclusive scan -> off[n+1] and cursors.
// ---------------------------------------------------------------------------
__global__ __launch_bounds__(1024) void scan_kernel(
    const int* __restrict__ counts, int* __restrict__ off,
    int* __restrict__ cur, int n) {
    __shared__ int sdata[1024];
    const int tid = threadIdx.x;
    const int per = (n + 1023) / 1024;
    const int lo = min(tid * per, n);
    const int hi = min(lo + per, n);
    int sum = 0;
#pragma unroll 4
    for (int i = lo; i < hi; ++i) sum += counts[i];
    sdata[tid] = sum;
    __syncthreads();
#pragma unroll
    for (int d = 1; d < 1024; d <<= 1) {
        int v = (tid >= d) ? sdata[tid - d] : 0;
        __syncthreads();
        sdata[tid] += v;
        __syncthreads();
    }
    int pre = (tid == 0) ? 0 : sdata[tid - 1];
#pragma unroll 4
    for (int i = lo; i < hi; ++i) {
        off[i] = pre;
        cur[i] = pre;
        pre += counts[i];
    }
    if (tid == 0) off[n] = sdata[1023];
}

// ---------------------------------------------------------------------------
// CSR build, pass 3: bin edge ids by source node.
// ---------------------------------------------------------------------------
__global__ void fill_kernel(const int* __restrict__ src, int* __restrict__ cur,
                            int* __restrict__ eid, int nedges) {
    int e = blockIdx.x * 256 + threadIdx.x;
    if (e < nedges) {
        int slot = atomicAdd(&cur[src[e]], 1);
        eid[slot] = e;
    }
}

// ---------------------------------------------------------------------------
// Gather: sum node's edge rows; write agg PACKED split-bf16 (hi|lo per elem).
// One wave per node, float2 per lane; unroll-8 (8 rows in flight).
// ---------------------------------------------------------------------------
__global__ __launch_bounds__(256) void gather_kernel(
    const float* __restrict__ edge_attr, const int* __restrict__ eid,
    const int* __restrict__ off, unsigned int* __restrict__ aggp, int nnodes) {
    int node = blockIdx.x * 4 + (threadIdx.x >> 6);
    int lane = threadIdx.x & 63;
    if (node >= nnodes) return;
    int s = off[node];
    int e = off[node + 1];
    float2 acc = make_float2(0.f, 0.f);
    int i = s;
    for (; i + 8 <= e; i += 8) {
        int eb[8];
#pragma unroll
        for (int u = 0; u < 8; ++u) eb[u] = eid[i + u];
#pragma unroll
        for (int u = 0; u < 8; ++u) {
            float2 v = *((const float2*)(edge_attr + (size_t)eb[u] * D) + lane);
            acc.x += v.x;
            acc.y += v.y;
        }
    }
    for (; i < e; ++i) {
        float2 v = *((const float2*)(edge_attr + (size_t)eid[i] * D) + lane);
        acc.x += v.x;
        acc.y += v.y;
    }
    uint2 p;
    p.x = packf(acc.x);
    p.y = packf(acc.y);
    *((uint2*)(aggp + (size_t)node * D) + lane) = p;
}

// ---------------------------------------------------------------------------
// Split x (f32) -> packed split-bf16 plane. float4 -> uint4, grid-stride-free.
// ---------------------------------------------------------------------------
__global__ void split_kernel(const float* __restrict__ x,
                             unsigned int* __restrict__ xp, int n4) {
    int i = blockIdx.x * 256 + threadIdx.x;
    if (i < n4) {
        float4 v = ((const float4*)x)[i];
        uint4 p;
        p.x = packf(v.x);
        p.y = packf(v.y);
        p.z = packf(v.z);
        p.w = packf(v.w);
        ((uint4*)xp)[i] = p;
    }
}

// ---------------------------------------------------------------------------
// W1 (f32 [K][128]) -> frag-major transposed bf16 planes:
//   Wh[((k>>3)*128 + j)*8 + (k&7)] so a wave's bfrag load is 4x256B segments.
// grid = 128 (col j), block = K threads (k).
// ---------------------------------------------------------------------------
__global__ void prep_w_kernel(const float* __restrict__ W,
                              unsigned short* __restrict__ Wh,
                              unsigned short* __restrict__ Wl) {
    int j = blockIdx.x;
    int k = threadIdx.x;
    float w = W[(size_t)k * D + j];
    unsigned int hi = bf16_rn(w);
    size_t o = (size_t)((k >> 3) * 128 + j) * 8 + (k & 7);
    Wh[o] = (unsigned short)hi;
    Wl[o] = (unsigned short)bf16_rn(w - bf16_f(hi));
}

// ---------------------------------------------------------------------------
// Fold BN (batch stats) into next layer's W; emit frag-major split planes
// and f32 bias. grid = 128 (col j), block = 128 (k).
// ---------------------------------------------------------------------------
__global__ void fold_kernel(const float* __restrict__ sum,
                            const float* __restrict__ sq,
                            const float* __restrict__ gamma,
                            const float* __restrict__ beta,
                            const float* __restrict__ W,
                            const float* __restrict__ b,
                            unsigned short* __restrict__ Wh,
                            unsigned short* __restrict__ Wl,
                            float* __restrict__ bf, float invM) {
    int j = blockIdx.x;
    int k = threadIdx.x;
    float mean = sum[k] * invM;
    float var = sq[k] * invM - mean * mean;
    float scale = gamma[k] * rsqrtf(var + 1e-5f);
    float shift = beta[k] - mean * scale;
    float w = W[k * D + j];
    float wf = scale * w;
    unsigned int hi = bf16_rn(wf);
    size_t o = (size_t)((k >> 3) * 128 + j) * 8 + (k & 7);
    Wh[o] = (unsigned short)hi;
    Wl[o] = (unsigned short)bf16_rn(wf - bf16_f(hi));
    float v = shift * w;
#pragma unroll
    for (int of = 32; of; of >>= 1) v += __shfl_down(v, of);
    __shared__ float ws2[2];
    if ((k & 63) == 0) ws2[k >> 6] = v;
    __syncthreads();
    if (k == 0) bf[j] = b[j] + ws2[0] + ws2[1];
}

// ---------------------------------------------------------------------------
// Split-bf16 MFMA GEMM, pre-split packed A (uint = hi|lo), frag-major W.
// C = act(A[M,K] @ Wt^T + bias). 3 MFMAs per tile: Ah*Wh + Ah*Wl + Al*Wh.
// Block = 256 thr = 4 waves; BM = 128 (wave: 2 row-tiles x 8 col-tiles).
// Hot loop: 4 A-loads (uint4 pairs) + 16 B-loads + 16 v_perm + 48 MFMA.
// K==256: k<128 from A0, k>=128 from A1 (implicit concat).
// C/D layout (m89): col = lane&15, row = (lane>>4)*4 + reg.
// ---------------------------------------------------------------------------
template <int K, bool SILU, bool STATS, bool PACKOUT>
__global__ __launch_bounds__(256, 2) void gemm_mfma(
    const unsigned int* __restrict__ A0, const unsigned int* __restrict__ A1,
    const unsigned short* __restrict__ Wh,
    const unsigned short* __restrict__ Wl,
    const float* __restrict__ bias, unsigned int* __restrict__ Cp,
    float* __restrict__ Cf, float* __restrict__ gsum,
    float* __restrict__ gsq, int M) {
    constexpr int NS = K / 32;
    const int tid = threadIdx.x;
    const int w = tid >> 6;
    const int l = tid & 63;
    const int lr = l & 15;   // row-in-tile (A) / col-in-tile (W)
    const int lk = l >> 4;   // k-quarter 0..3
    const int row0 = blockIdx.x * 128 + w * 32;

    facc acc[2][8];
#pragma unroll
    for (int rt = 0; rt < 2; ++rt)
#pragma unroll
        for (int ct = 0; ct < 8; ++ct)
#pragma unroll
            for (int r = 0; r < 4; ++r) acc[rt][ct][r] = 0.f;

    for (int s = 0; s < NS; ++s) {
        const int kb = s * 32 + lk * 8;
        bfrag ah[2], al[2];
#pragma unroll
        for (int rt = 0; rt < 2; ++rt) {
            const int arow = row0 + rt * 16 + lr;
            const unsigned int* As = A0;
            int kk = kb;
            if (K == 256 && s >= 4) { As = A1; kk = kb - 128; }
            u32x4 q0 = {0u, 0u, 0u, 0u}, q1 = {0u, 0u, 0u, 0u};
            if (arow < M) {
                const u32x4* p = (const u32x4*)(As + (size_t)arow * D + kk);
                q0 = p[0];
                q1 = p[1];
            }
            unsigned int ua[8] = {q0.x, q0.y, q0.z, q0.w,
                                  q1.x, q1.y, q1.z, q1.w};
            u32x4 uh, ul;
#pragma unroll
            for (int r = 0; r < 4; ++r) {
                uh[r] = __builtin_amdgcn_perm(ua[2 * r + 1], ua[2 * r],
                                              0x07060302u);
                ul[r] = __builtin_amdgcn_perm(ua[2 * r + 1], ua[2 * r],
                                              0x05040100u);
            }
            ah[rt] = __builtin_bit_cast(bfrag, uh);
            al[rt] = __builtin_bit_cast(bfrag, ul);
        }
        bfrag bh[8], bl[8];
        const int fb = (s * 4 + lk) * 128;
#pragma unroll
        for (int ct = 0; ct < 8; ++ct) {
            size_t o = (size_t)(fb + ct * 16 + lr) * 8;
            bh[ct] = *(const bfrag*)(Wh + o);
            bl[ct] = *(const bfrag*)(Wl + o);
        }
#pragma unroll
        for (int rt = 0; rt < 2; ++rt)
#pragma unroll
            for (int ct = 0; ct < 8; ++ct)
                acc[rt][ct] = mfma16(ah[rt], bh[ct], acc[rt][ct]);
#pragma unroll
        for (int rt = 0; rt < 2; ++rt)
#pragma unroll
            for (int ct = 0; ct < 8; ++ct)
                acc[rt][ct] = mfma16(ah[rt], bl[ct], acc[rt][ct]);
#pragma unroll
        for (int rt = 0; rt < 2; ++rt)
#pragma unroll
            for (int ct = 0; ct < 8; ++ct)
                acc[rt][ct] = mfma16(al[rt], bh[ct], acc[rt][ct]);
    }

    // Epilogue: bias, SiLU, packed/f32 store, per-column stats.
    __shared__ float sred[2][4][128];
#pragma unroll
    for (int ct = 0; ct < 8; ++ct) {
        const int col = ct * 16 + lr;
        const float bj = bias[col];
        float s = 0.f, q = 0.f;
#pragma unroll
        for (int rt = 0; rt < 2; ++rt) {
            const int base = row0 + rt * 16 + lk * 4;
#pragma unroll
            for (int r = 0; r < 4; ++r) {
                int crow = base + r;
                if (crow < M) {
                    float v = acc[rt][ct][r] + bj;
                    if (SILU) v = v / (1.0f + __expf(-v));
                    if (PACKOUT) Cp[(size_t)crow * D + col] = packf(v);
                    else         Cf[(size_t)crow * D + col] = v;
                    if (STATS) { s += v; q += v * v; }
                }
            }
        }
        if (STATS) {
            s += __shfl_xor(s, 16);
            s += __shfl_xor(s, 32);
            q += __shfl_xor(q, 16);
            q += __shfl_xor(q, 32);
            if (lk == 0) {
                sred[0][w][col] = s;
                sred[1][w][col] = q;
            }
        }
    }
    if (STATS) {
        __syncthreads();
        if (tid < 128) {
            float v = sred[0][0][tid] + sred[0][1][tid] + sred[0][2][tid] +
                      sred[0][3][tid];
            unsafeAtomicAdd(&gsum[tid], v);
        } else {
            int c = tid - 128;
            float v = sred[1][0][c] + sred[1][1][c] + sred[1][2][c] +
                      sred[1][3][c];
            unsafeAtomicAdd(&gsq[c], v);
        }
    }
}

extern "C" void kernel_launch(void* const* d_in, const int* in_sizes, int n_in,
                              void* d_out, int out_size, void* d_ws,
                              size_t ws_size, hipStream_t stream) {
    const float* x     = (const float*)d_in[0];
    const int*   eidx  = (const int*)d_in[1];
    const float* eattr = (const float*)d_in[2];
    const float* W1  = (const float*)d_in[3];
    const float* b1  = (const float*)d_in[4];
    const float* g1  = (const float*)d_in[5];
    const float* be1 = (const float*)d_in[6];
    const float* W2  = (const float*)d_in[7];
    const float* b2  = (const float*)d_in[8];
    const float* g2  = (const float*)d_in[9];
    const float* be2 = (const float*)d_in[10];
    const float* W3  = (const float*)d_in[11];
    const float* b3  = (const float*)d_in[12];

    const int M = in_sizes[0] / D;   // 50000
    const int E = in_sizes[1] / 2;   // 600000
    const int* srcIdx = eidx;

    unsigned int* wsu = (unsigned int*)d_ws;
    unsigned int* aggp = wsu;                       // M*D packed
    unsigned int* xp   = aggp + (size_t)M * D;      // M*D
    unsigned int* h1p  = xp + (size_t)M * D;        // M*D
    unsigned int* h2p  = h1p + (size_t)M * D;       // M*D
    float* sum1 = (float*)(h2p + (size_t)M * D);    // D
    float* sq1  = sum1 + D;
    float* sum2 = sq1 + D;
    float* sq2  = sum2 + D;
    float* b2f  = sq2 + D;                          // D
    float* b3f  = b2f + D;                          // D
    int* counts = (int*)(b3f + D);                  // M
    int* off    = counts + M;                       // M+4
    int* cur    = off + M + 4;                      // M
    int* eid    = cur + M;                          // E
    unsigned short* W1h = (unsigned short*)(eid + E);  // 128*256
    unsigned short* W1l = W1h + 256 * D;
    unsigned short* W2h = W1l + 256 * D;               // 128*128
    unsigned short* W2l = W2h + D * D;
    unsigned short* W3h = W2l + D * D;
    unsigned short* W3l = W3h + D * D;

    float* out = (float*)d_out;

    hipMemsetAsync(counts, 0, (size_t)M * sizeof(int), stream);
    hipMemsetAsync(sum1, 0, 4 * D * sizeof(float), stream);

    int eblk = (E + 255) / 256;
    hist_kernel<<<eblk, 256, 0, stream>>>(srcIdx, counts, E);
    scan_kernel<<<1, 1024, 0, stream>>>(counts, off, cur, M);
    fill_kernel<<<eblk, 256, 0, stream>>>(srcIdx, cur, eid, E);
    gather_kernel<<<(M + 3) / 4, 256, 0, stream>>>(eattr, eid, off, aggp, M);

    split_kernel<<<(M * 32 + 255) / 256, 256, 0, stream>>>(x, xp, M * 32);
    prep_w_kernel<<<D, 256, 0, stream>>>(W1, W1h, W1l);

    int nblk = (M + 127) / 128;
    gemm_mfma<256, true, true, true><<<nblk, 256, 0, stream>>>(
        xp, aggp, W1h, W1l, b1, h1p, nullptr, sum1, sq1, M);
    fold_kernel<<<D, D, 0, stream>>>(sum1, sq1, g1, be1, W2, b2, W2h, W2l,
                                     b2f, 1.0f / (float)M);
    gemm_mfma<128, true, true, true><<<nblk, 256, 0, stream>>>(
        h1p, nullptr, W2h, W2l, b2f, h2p, nullptr, sum2, sq2, M);
    fold_kernel<<<D, D, 0, stream>>>(sum2, sq2, g2, be2, W3, b3, W3h, W3l,
                                     b3f, 1.0f / (float)M);
    gemm_mfma<128, false, false, false><<<nblk, 256, 0, stream>>>(
        h2p, nullptr, W3h, W3l, b3f, nullptr, out, nullptr, nullptr, M);
}

// Round 5
// 247.706 us; speedup vs baseline: 1.6489x; 1.1701x over previous
//
#include <hip/hip_runtime.h>
#include <hip/hip_bf16.h>

#define D 128

typedef __attribute__((ext_vector_type(8))) short bfrag;   // 8 bf16 (4 VGPRs)
typedef __attribute__((ext_vector_type(4))) float facc;    // 4 f32 acc
typedef __attribute__((ext_vector_type(4))) unsigned int u32x4;
typedef __attribute__((ext_vector_type(4))) float f32x4;

__device__ __forceinline__ facc mfma16(bfrag a, bfrag b, facc c) {
    return __builtin_amdgcn_mfma_f32_16x16x32_bf16(a, b, c, 0, 0, 0);
}
__device__ __forceinline__ unsigned int bf16_rn(float f) {
    unsigned int u = __float_as_uint(f);
    u += 0x7FFF + ((u >> 16) & 1);   // round-nearest-even
    return u >> 16;
}
__device__ __forceinline__ float bf16_f(unsigned int h) {
    return __uint_as_float(h << 16);
}
// pack f32 -> (bf16_hi << 16) | bf16_lo  (hi + lo reconstructs ~f32)
__device__ __forceinline__ unsigned int packf(float v) {
    unsigned int hi = bf16_rn(v);
    unsigned int lo = bf16_rn(v - bf16_f(hi));
    return (hi << 16) | lo;
}

// ---------------------------------------------------------------------------
// Fused prep: [0,eblk) histogram of src; [eblk,eblk+sblk) split x -> packed;
// [eblk+sblk, +128) W1 -> frag-major split-bf16 planes. All 256-thread.
// ---------------------------------------------------------------------------
__global__ __launch_bounds__(256) void prep_kernel(
    const int* __restrict__ src, int* __restrict__ counts, int nedges,
    const float* __restrict__ x, unsigned int* __restrict__ xp, int n4,
    const float* __restrict__ W1, unsigned short* __restrict__ Wh,
    unsigned short* __restrict__ Wl, int eblk, int sblk) {
    int b = blockIdx.x;
    if (b < eblk) {
        int e = b * 256 + threadIdx.x;
        if (e < nedges) atomicAdd(&counts[src[e]], 1);
    } else if (b < eblk + sblk) {
        int i = (b - eblk) * 256 + threadIdx.x;
        if (i < n4) {
            float4 v = ((const float4*)x)[i];
            uint4 p;
            p.x = packf(v.x);
            p.y = packf(v.y);
            p.z = packf(v.z);
            p.w = packf(v.w);
            ((uint4*)xp)[i] = p;
        }
    } else {
        int j = b - eblk - sblk;   // 0..127 output col
        int k = threadIdx.x;       // 0..255
        float w = W1[(size_t)k * D + j];
        unsigned int hi = bf16_rn(w);
        size_t o = (size_t)((k >> 3) * 128 + j) * 8 + (k & 7);
        Wh[o] = (unsigned short)hi;
        Wl[o] = (unsigned short)bf16_rn(w - bf16_f(hi));
    }
}

// ---------------------------------------------------------------------------
// Multi-block exclusive scan of counts[n] (3 passes). CHUNK = 2048/block.
// ---------------------------------------------------------------------------
#define SCHUNK 2048
__global__ __launch_bounds__(256) void scan1_kernel(
    const int* __restrict__ counts, int* __restrict__ bsum, int n) {
    __shared__ int sd[256];
    const int tid = threadIdx.x;
    const int base = blockIdx.x * SCHUNK + tid * 8;
    int s = 0;
#pragma unroll
    for (int j = 0; j < 8; ++j) {
        int idx = base + j;
        if (idx < n) s += counts[idx];
    }
    sd[tid] = s;
    __syncthreads();
    for (int d2 = 128; d2; d2 >>= 1) {
        if (tid < d2) sd[tid] += sd[tid + d2];
        __syncthreads();
    }
    if (tid == 0) bsum[blockIdx.x] = sd[0];
}
// single wave inclusive scan over nb block sums (nb <= 64)
__global__ void scan2_kernel(int* __restrict__ bsum, int nb) {
    int tid = threadIdx.x;
    int v = (tid < nb) ? bsum[tid] : 0;
#pragma unroll
    for (int d2 = 1; d2 < 64; d2 <<= 1) {
        int t = __shfl_up(v, d2);
        if (tid >= d2) v += t;
    }
    if (tid < nb) bsum[tid] = v;
}
__global__ __launch_bounds__(256) void scan3_kernel(
    const int* __restrict__ counts, const int* __restrict__ bsum,
    int* __restrict__ off, int* __restrict__ cur, int n) {
    __shared__ int sd[256];
    const int tid = threadIdx.x;
    const int base = blockIdx.x * SCHUNK + tid * 8;
    int loc[8];
    int s = 0;
#pragma unroll
    for (int j = 0; j < 8; ++j) {
        int idx = base + j;
        int c = (idx < n) ? counts[idx] : 0;
        loc[j] = c;
        s += c;
    }
    sd[tid] = s;
    __syncthreads();
#pragma unroll
    for (int d2 = 1; d2 < 256; d2 <<= 1) {
        int t = (tid >= d2) ? sd[tid - d2] : 0;
        __syncthreads();
        sd[tid] += t;
        __syncthreads();
    }
    int boff = (blockIdx.x == 0) ? 0 : bsum[blockIdx.x - 1];
    int pre = boff + sd[tid] - s;   // exclusive prefix
#pragma unroll
    for (int j = 0; j < 8; ++j) {
        int idx = base + j;
        if (idx < n) {
            off[idx] = pre;
            cur[idx] = pre;
            pre += loc[j];
        }
    }
    if (tid == 255 && base + 8 >= n && n <= blockIdx.x * SCHUNK + SCHUNK)
        off[n] = boff + sd[255];
}

// ---------------------------------------------------------------------------
// CSR fill: bin edge ids by source node.
// ---------------------------------------------------------------------------
__global__ void fill_kernel(const int* __restrict__ src, int* __restrict__ cur,
                            int* __restrict__ eid, int nedges) {
    int e = blockIdx.x * 256 + threadIdx.x;
    if (e < nedges) {
        int slot = atomicAdd(&cur[src[e]], 1);
        eid[slot] = e;
    }
}

// ---------------------------------------------------------------------------
// Gather v3: one wave per node. 2 rows per load instruction (half-wave h
// reads row eid[i+2u+h], lanes (l&31) own 4 cols), 16 rows in flight,
// nontemporal loads (zero reuse). Final shfl_xor(32) combines halves; lanes
// 0..31 write the packed split-bf16 agg row (512B).
// ---------------------------------------------------------------------------
__global__ __launch_bounds__(256) void gather_kernel(
    const float* __restrict__ edge_attr, const int* __restrict__ eid,
    const int* __restrict__ off, unsigned int* __restrict__ aggp, int nnodes) {
    int node = blockIdx.x * 4 + (threadIdx.x >> 6);
    int lane = threadIdx.x & 63;
    if (node >= nnodes) return;
    const int h = lane >> 5;
    const int c = lane & 31;
    int i = off[node];
    const int e = off[node + 1];
    f32x4 acc = {0.f, 0.f, 0.f, 0.f};

    if (i < e && (i & 1)) {   // align to even for int2 eid loads
        f32x4 v = __builtin_nontemporal_load(
            (const f32x4*)(edge_attr + (size_t)eid[i] * D) + c);
        if (h == 0) acc += v;
        ++i;
    }
    for (; i + 16 <= e; i += 16) {
        f32x4 v[8];
#pragma unroll
        for (int u = 0; u < 8; ++u) {
            int2 ep = *(const int2*)(eid + i + 2 * u);
            int row = h ? ep.y : ep.x;
            v[u] = __builtin_nontemporal_load(
                (const f32x4*)(edge_attr + (size_t)row * D) + c);
        }
#pragma unroll
        for (int u = 0; u < 8; ++u) acc += v[u];
    }
    for (; i + 2 <= e; i += 2) {
        int2 ep = *(const int2*)(eid + i);
        int row = h ? ep.y : ep.x;
        acc += __builtin_nontemporal_load(
            (const f32x4*)(edge_attr + (size_t)row * D) + c);
    }
    if (i < e) {
        f32x4 v = __builtin_nontemporal_load(
            (const f32x4*)(edge_attr + (size_t)eid[i] * D) + c);
        if (h == 0) acc += v;
    }
#pragma unroll
    for (int r = 0; r < 4; ++r) acc[r] += __shfl_xor(acc[r], 32);
    if (h == 0) {
        u32x4 p;
#pragma unroll
        for (int r = 0; r < 4; ++r) p[r] = packf(acc[r]);
        *((u32x4*)(aggp + (size_t)node * D) + c) = p;
    }
}

// ---------------------------------------------------------------------------
// Fold BN (batch stats) into next layer's W; frag-major split planes + bias.
// ---------------------------------------------------------------------------
__global__ void fold_kernel(const float* __restrict__ sum,
                            const float* __restrict__ sq,
                            const float* __restrict__ gamma,
                            const float* __restrict__ beta,
                            const float* __restrict__ W,
                            const float* __restrict__ b,
                            unsigned short* __restrict__ Wh,
                            unsigned short* __restrict__ Wl,
                            float* __restrict__ bf, float invM) {
    int j = blockIdx.x;
    int k = threadIdx.x;
    float mean = sum[k] * invM;
    float var = sq[k] * invM - mean * mean;
    float scale = gamma[k] * rsqrtf(var + 1e-5f);
    float shift = beta[k] - mean * scale;
    float w = W[k * D + j];
    float wf = scale * w;
    unsigned int hi = bf16_rn(wf);
    size_t o = (size_t)((k >> 3) * 128 + j) * 8 + (k & 7);
    Wh[o] = (unsigned short)hi;
    Wl[o] = (unsigned short)bf16_rn(wf - bf16_f(hi));
    float v = shift * w;
#pragma unroll
    for (int of = 32; of; of >>= 1) v += __shfl_down(v, of);
    __shared__ float ws2[2];
    if ((k & 63) == 0) ws2[k >> 6] = v;
    __syncthreads();
    if (k == 0) bf[j] = b[j] + ws2[0] + ws2[1];
}

// ---------------------------------------------------------------------------
// Split-bf16 MFMA GEMM, pre-split packed A (uint = hi|lo), frag-major W.
// 3 MFMAs per tile: Ah*Wh + Ah*Wl + Al*Wh. Block = 4 waves, BM = 128.
// C/D layout (m89): col = lane&15, row = (lane>>4)*4 + reg.
// ---------------------------------------------------------------------------
template <int K, bool SILU, bool STATS, bool PACKOUT>
__global__ __launch_bounds__(256, 2) void gemm_mfma(
    const unsigned int* __restrict__ A0, const unsigned int* __restrict__ A1,
    const unsigned short* __restrict__ Wh,
    const unsigned short* __restrict__ Wl,
    const float* __restrict__ bias, unsigned int* __restrict__ Cp,
    float* __restrict__ Cf, float* __restrict__ gsum,
    float* __restrict__ gsq, int M) {
    constexpr int NS = K / 32;
    const int tid = threadIdx.x;
    const int w = tid >> 6;
    const int l = tid & 63;
    const int lr = l & 15;
    const int lk = l >> 4;
    const int row0 = blockIdx.x * 128 + w * 32;

    facc acc[2][8];
#pragma unroll
    for (int rt = 0; rt < 2; ++rt)
#pragma unroll
        for (int ct = 0; ct < 8; ++ct)
#pragma unroll
            for (int r = 0; r < 4; ++r) acc[rt][ct][r] = 0.f;

    for (int s = 0; s < NS; ++s) {
        const int kb = s * 32 + lk * 8;
        bfrag ah[2], al[2];
#pragma unroll
        for (int rt = 0; rt < 2; ++rt) {
            const int arow = row0 + rt * 16 + lr;
            const unsigned int* As = A0;
            int kk = kb;
            if (K == 256 && s >= 4) { As = A1; kk = kb - 128; }
            u32x4 q0 = {0u, 0u, 0u, 0u}, q1 = {0u, 0u, 0u, 0u};
            if (arow < M) {
                const u32x4* p = (const u32x4*)(As + (size_t)arow * D + kk);
                q0 = p[0];
                q1 = p[1];
            }
            unsigned int ua[8] = {q0.x, q0.y, q0.z, q0.w,
                                  q1.x, q1.y, q1.z, q1.w};
            u32x4 uh, ul;
#pragma unroll
            for (int r = 0; r < 4; ++r) {
                uh[r] = __builtin_amdgcn_perm(ua[2 * r + 1], ua[2 * r],
                                              0x07060302u);
                ul[r] = __builtin_amdgcn_perm(ua[2 * r + 1], ua[2 * r],
                                              0x05040100u);
            }
            ah[rt] = __builtin_bit_cast(bfrag, uh);
            al[rt] = __builtin_bit_cast(bfrag, ul);
        }
        bfrag bh[8], bl[8];
        const int fb = (s * 4 + lk) * 128;
#pragma unroll
        for (int ct = 0; ct < 8; ++ct) {
            size_t o = (size_t)(fb + ct * 16 + lr) * 8;
            bh[ct] = *(const bfrag*)(Wh + o);
            bl[ct] = *(const bfrag*)(Wl + o);
        }
#pragma unroll
        for (int rt = 0; rt < 2; ++rt)
#pragma unroll
            for (int ct = 0; ct < 8; ++ct)
                acc[rt][ct] = mfma16(ah[rt], bh[ct], acc[rt][ct]);
#pragma unroll
        for (int rt = 0; rt < 2; ++rt)
#pragma unroll
            for (int ct = 0; ct < 8; ++ct)
                acc[rt][ct] = mfma16(ah[rt], bl[ct], acc[rt][ct]);
#pragma unroll
        for (int rt = 0; rt < 2; ++rt)
#pragma unroll
            for (int ct = 0; ct < 8; ++ct)
                acc[rt][ct] = mfma16(al[rt], bh[ct], acc[rt][ct]);
    }

    __shared__ float sred[2][4][128];
#pragma unroll
    for (int ct = 0; ct < 8; ++ct) {
        const int col = ct * 16 + lr;
        const float bj = bias[col];
        float s = 0.f, q = 0.f;
#pragma unroll
        for (int rt = 0; rt < 2; ++rt) {
            const int base = row0 + rt * 16 + lk * 4;
#pragma unroll
            for (int r = 0; r < 4; ++r) {
                int crow = base + r;
                if (crow < M) {
                    float v = acc[rt][ct][r] + bj;
                    if (SILU) v = v / (1.0f + __expf(-v));
                    if (PACKOUT) Cp[(size_t)crow * D + col] = packf(v);
                    else         Cf[(size_t)crow * D + col] = v;
                    if (STATS) { s += v; q += v * v; }
                }
            }
        }
        if (STATS) {
            s += __shfl_xor(s, 16);
            s += __shfl_xor(s, 32);
            q += __shfl_xor(q, 16);
            q += __shfl_xor(q, 32);
            if (lk == 0) {
                sred[0][w][col] = s;
                sred[1][w][col] = q;
            }
        }
    }
    if (STATS) {
        __syncthreads();
        if (tid < 128) {
            float v = sred[0][0][tid] + sred[0][1][tid] + sred[0][2][tid] +
                      sred[0][3][tid];
            unsafeAtomicAdd(&gsum[tid], v);
        } else {
            int c = tid - 128;
            float v = sred[1][0][c] + sred[1][1][c] + sred[1][2][c] +
                      sred[1][3][c];
            unsafeAtomicAdd(&gsq[c], v);
        }
    }
}

extern "C" void kernel_launch(void* const* d_in, const int* in_sizes, int n_in,
                              void* d_out, int out_size, void* d_ws,
                              size_t ws_size, hipStream_t stream) {
    const float* x     = (const float*)d_in[0];
    const int*   eidx  = (const int*)d_in[1];
    const float* eattr = (const float*)d_in[2];
    const float* W1  = (const float*)d_in[3];
    const float* b1  = (const float*)d_in[4];
    const float* g1  = (const float*)d_in[5];
    const float* be1 = (const float*)d_in[6];
    const float* W2  = (const float*)d_in[7];
    const float* b2  = (const float*)d_in[8];
    const float* g2  = (const float*)d_in[9];
    const float* be2 = (const float*)d_in[10];
    const float* W3  = (const float*)d_in[11];
    const float* b3  = (const float*)d_in[12];

    const int M = in_sizes[0] / D;   // 50000
    const int E = in_sizes[1] / 2;   // 600000
    const int* srcIdx = eidx;

    unsigned int* wsu = (unsigned int*)d_ws;
    unsigned int* aggp = wsu;                       // M*D packed
    unsigned int* xp   = aggp + (size_t)M * D;      // M*D
    unsigned int* h1p  = xp + (size_t)M * D;        // M*D
    unsigned int* h2p  = h1p + (size_t)M * D;       // M*D
    float* sum1 = (float*)(h2p + (size_t)M * D);    // D
    float* sq1  = sum1 + D;
    float* sum2 = sq1 + D;
    float* sq2  = sum2 + D;
    float* b2f  = sq2 + D;
    float* b3f  = b2f + D;
    int* counts = (int*)(b3f + D);                  // M
    int* off    = counts + M;                       // M+4
    int* cur    = off + M + 4;                      // M
    int* eid    = cur + M;                          // E
    int* bsum   = eid + E;                          // 64
    unsigned short* W1h = (unsigned short*)(bsum + 64);  // 128*256
    unsigned short* W1l = W1h + 256 * D;
    unsigned short* W2h = W1l + 256 * D;                 // 128*128
    unsigned short* W2l = W2h + D * D;
    unsigned short* W3h = W2l + D * D;
    unsigned short* W3l = W3h + D * D;

    float* out = (float*)d_out;

    hipMemsetAsync(counts, 0, (size_t)M * sizeof(int), stream);
    hipMemsetAsync(sum1, 0, 4 * D * sizeof(float), stream);

    const int eblk = (E + 255) / 256;
    const int sblk = (M * 32 + 255) / 256;
    prep_kernel<<<eblk + sblk + 128, 256, 0, stream>>>(
        srcIdx, counts, E, x, xp, M * 32, W1, W1h, W1l, eblk, sblk);

    const int nb = (M + SCHUNK - 1) / SCHUNK;   // 25 (<=64)
    scan1_kernel<<<nb, 256, 0, stream>>>(counts, bsum, M);
    scan2_kernel<<<1, 64, 0, stream>>>(bsum, nb);
    scan3_kernel<<<nb, 256, 0, stream>>>(counts, bsum, off, cur, M);
    fill_kernel<<<eblk, 256, 0, stream>>>(srcIdx, cur, eid, E);
    gather_kernel<<<(M + 3) / 4, 256, 0, stream>>>(eattr, eid, off, aggp, M);

    int nblk = (M + 127) / 128;
    gemm_mfma<256, true, true, true><<<nblk, 256, 0, stream>>>(
        xp, aggp, W1h, W1l, b1, h1p, nullptr, sum1, sq1, M);
    fold_kernel<<<D, D, 0, stream>>>(sum1, sq1, g1, be1, W2, b2, W2h, W2l,
                                     b2f, 1.0f / (float)M);
    gemm_mfma<128, true, true, true><<<nblk, 256, 0, stream>>>(
        h1p, nullptr, W2h, W2l, b2f, h2p, nullptr, sum2, sq2, M);
    fold_kernel<<<D, D, 0, stream>>>(sum2, sq2, g2, be2, W3, b3, W3h, W3l,
                                     b3f, 1.0f / (float)M);
    gemm_mfma<128, false, false, false><<<nblk, 256, 0, stream>>>(
        h2p, nullptr, W3h, W3l, b3f, nullptr, out, nullptr, nullptr, M);
}